// Round 2
// baseline (301.689 us; speedup 1.0000x reference)
//
#include <hip/hip_runtime.h>
#include <hip/hip_bf16.h>

// SVXSoftmax: cos = norm(input) @ norm(weight)^T ; margin transform ; *32
// B=512, D=512, C=100000.  out[512][100000] f32.
//
// Structure (r2): prep computes gt + bf16-normalized input (512KB, L2-resident).
// GEMM: 1 block per 64 classes. Phase 0: read 64 W rows f32 (the ONLY HBM read
// of W chip-wide), row-invnorm in-reg, convert->bf16 into XOR-swizzled LDS.
// K-loop: NO barriers — B from LDS, A fragments straight from L2. Epilogue fused.

#define S_SCALE 32.0f
#define MARGIN  0.35f
#define T_BOOST 0.2f
#define EPSN    1e-12f

constexpr int Bn = 512;      // batch (= full M tile)
constexpr int Dn = 512;      // dim
constexpr int Cn = 100000;   // classes
constexpr int BN = 64;       // classes per block

typedef __attribute__((ext_vector_type(8))) short bf16x8;
typedef __attribute__((ext_vector_type(4))) float f32x4;

static __device__ inline unsigned short f32_bf16(float f) {
    unsigned int u = __float_as_uint(f);
    u += 0x7FFFu + ((u >> 16) & 1u);     // round-to-nearest-even
    return (unsigned short)(u >> 16);
}

// ---------------- kernel 1: input norms, gt[b], bf16 normalized input ----------------
__global__ __launch_bounds__(256) void prep_kernel(const float* __restrict__ in,
                                                   const float* __restrict__ w,
                                                   const int* __restrict__ label,
                                                   float* __restrict__ gt,
                                                   unsigned short* __restrict__ in_h) {
    int b = blockIdx.x;
    int t = threadIdx.x;
    const float* irow = in + (size_t)b * Dn;
    int lab = label[b];
    const float* wrow = w + (size_t)lab * Dn;
    float x0 = irow[t], x1 = irow[t + 256];
    float y0 = wrow[t], y1 = wrow[t + 256];
    float s_ii = x0 * x0 + x1 * x1;
    float s_ww = y0 * y0 + y1 * y1;
    float s_iw = x0 * y0 + x1 * y1;
    #pragma unroll
    for (int off = 32; off; off >>= 1) {
        s_ii += __shfl_xor(s_ii, off);
        s_ww += __shfl_xor(s_ww, off);
        s_iw += __shfl_xor(s_iw, off);
    }
    __shared__ float r0[4], r1[4], r2[4], bc[1];
    int wid = t >> 6;
    if ((t & 63) == 0) { r0[wid] = s_ii; r1[wid] = s_ww; r2[wid] = s_iw; }
    __syncthreads();
    if (t == 0) {
        float a = r0[0] + r0[1] + r0[2] + r0[3];
        float c = r1[0] + r1[1] + r1[2] + r1[3];
        float d = r2[0] + r2[1] + r2[2] + r2[3];
        float inv_i = 1.0f / fmaxf(sqrtf(a), EPSN);
        float g = d * inv_i / fmaxf(sqrtf(c), EPSN);
        g = fminf(fmaxf(g, -1.0f), 1.0f);
        gt[b] = g;
        bc[0] = inv_i;
    }
    __syncthreads();
    float inv_i = bc[0];
    in_h[(size_t)b * Dn + t]       = f32_bf16(x0 * inv_i);
    in_h[(size_t)b * Dn + t + 256] = f32_bf16(x1 * inv_i);
}

// ---------------- kernel 2: fused norm+convert+GEMM+margin ----------------
// 512 threads = 8 waves (4 M-groups x 2 N-groups); wave owns 128 M x 32 N.
// LDS: Bs[64 rows][512 k] bf16, byte-swizzle  off ^= (row&7)<<4  (bank-ideal
// for both the phase-0 strided writes and the K-loop ds_read_b128).
__global__ __launch_bounds__(512, 4) void gemm_kernel(const unsigned short* __restrict__ in_h,
                                                      const float* __restrict__ w,
                                                      const float* __restrict__ gt,
                                                      const int* __restrict__ label,
                                                      float* __restrict__ out) {
    __shared__ unsigned short Bs[BN * 512];   // 64 KB
    char* bsb = (char*)Bs;
    int t = threadIdx.x, wid = t >> 6, lane = t & 63;
    int cbase = blockIdx.x * BN;

    // ---- phase 0: W rows -> invnorm -> bf16 -> swizzled LDS ----
    {
        int rl = (wid << 3) | (lane >> 3);        // local row 0..63 (8 lanes/row)
        int rg = cbase + rl; if (rg >= Cn) rg = Cn - 1;
        const float* wr = w + (size_t)rg * Dn;
        int kc = lane & 7;                        // lane's 16B-piece id within 128B
        f32x4 vd[16];
        #pragma unroll
        for (int i = 0; i < 8; ++i) {             // piece i: floats kc*8 + i*64 .. +7
            vd[2*i]   = *(const f32x4*)(wr + kc * 8 + i * 64);
            vd[2*i+1] = *(const f32x4*)(wr + kc * 8 + i * 64 + 4);
        }
        float s = 0.f;
        #pragma unroll
        for (int j = 0; j < 16; ++j)
            s += vd[j][0]*vd[j][0] + vd[j][1]*vd[j][1] + vd[j][2]*vd[j][2] + vd[j][3]*vd[j][3];
        s += __shfl_xor(s, 1); s += __shfl_xor(s, 2); s += __shfl_xor(s, 4);
        float invn = 1.0f / fmaxf(sqrtf(s), EPSN);
        #pragma unroll
        for (int i = 0; i < 8; ++i) {
            bf16x8 hv;
            #pragma unroll
            for (int j = 0; j < 4; ++j) {
                hv[j]     = (short)f32_bf16(vd[2*i][j]   * invn);
                hv[4 + j] = (short)f32_bf16(vd[2*i+1][j] * invn);
            }
            int off = ((rl << 10) + (kc << 4) + (i << 7)) ^ ((rl & 7) << 4);
            *(bf16x8*)(bsb + off) = hv;
        }
    }
    __syncthreads();                              // the ONLY barrier

    // ---- K loop: no barriers. A from L2 (in_h), B from LDS ----
    int wm = wid >> 1, wn = wid & 1;
    int l15 = lane & 15, lk = lane >> 4;
    const unsigned short* abase = in_h + (size_t)(wm * 128 + l15) * Dn + lk * 8;
    int brow0 = wn * 32 + l15;

    f32x4 acc[8][2];
    #pragma unroll
    for (int m = 0; m < 8; ++m)
        #pragma unroll
        for (int n = 0; n < 2; ++n) acc[m][n] = (f32x4){0.f, 0.f, 0.f, 0.f};

    #pragma unroll
    for (int kt = 0; kt < Dn; kt += 32) {
        bf16x8 a[8], b[2];
        #pragma unroll
        for (int mf = 0; mf < 8; ++mf)
            a[mf] = *(const bf16x8*)(abase + mf * 16 * Dn + kt);
        #pragma unroll
        for (int nf = 0; nf < 2; ++nf) {
            int br = brow0 + nf * 16;
            int off = ((br << 10) + kt * 2 + (lk << 4)) ^ ((br & 7) << 4);
            b[nf] = *(const bf16x8*)(bsb + off);
        }
        #pragma unroll
        for (int mf = 0; mf < 8; ++mf)
            #pragma unroll
            for (int nf = 0; nf < 2; ++nf)
                acc[mf][nf] = __builtin_amdgcn_mfma_f32_16x16x32_bf16(a[mf], b[nf], acc[mf][nf], 0, 0, 0);
    }

    // ---- epilogue: clamp, margin, label scatter, scale ----
    #pragma unroll
    for (int mf = 0; mf < 8; ++mf) {
        #pragma unroll
        for (int r = 0; r < 4; ++r) {
            int b_row = wm * 128 + mf * 16 + lk * 4 + r;
            float g   = gt[b_row];
            int lab   = label[b_row];
            float thr = g - MARGIN;
            float gv  = thr * S_SCALE;
            size_t obase = (size_t)b_row * Cn;
            #pragma unroll
            for (int nf = 0; nf < 2; ++nf) {
                int c = cbase + wn * 32 + nf * 16 + l15;
                if (c < Cn) {
                    float cosv = acc[mf][nf][r];
                    cosv = fminf(fmaxf(cosv, -1.0f), 1.0f);
                    float o = (cosv > thr) ? ((T_BOOST + 1.0f) * cosv + T_BOOST) : cosv;
                    o *= S_SCALE;
                    if (c == lab) o = gv;
                    out[obase + c] = o;
                }
            }
        }
    }
}

extern "C" void kernel_launch(void* const* d_in, const int* in_sizes, int n_in,
                              void* d_out, int out_size, void* d_ws, size_t ws_size,
                              hipStream_t stream) {
    const float* in  = (const float*)d_in[0];
    const float* w   = (const float*)d_in[1];
    const int* label = (const int*)d_in[2];
    float* out = (float*)d_out;

    char* ws = (char*)d_ws;
    float* gt            = (float*)ws;                 // 512 f32
    unsigned short* in_h = (unsigned short*)(ws + 4096); // 512*512 bf16 = 512 KB

    prep_kernel<<<dim3(Bn), dim3(256), 0, stream>>>(in, w, label, gt, in_h);
    gemm_kernel<<<dim3((Cn + BN - 1) / BN), dim3(512), 0, stream>>>(in_h, w, gt, label, out);
}

// Round 3
// 164.920 us; speedup vs baseline: 1.8293x; 1.8293x over previous
//
#include <hip/hip_runtime.h>
#include <hip/hip_bf16.h>

// SVXSoftmax: cos = norm(input) @ norm(weight)^T ; margin transform ; *32
// B=512, D=512, C=100000.  out[512][100000] f32.
//
// r3: prep packs bf16-normalized input in MFMA-fragment order (A-loads become
// 1KB coalesced L2 streams). GEMM: block = 64 classes, full-K B tile in
// swizzled LDS (one barrier), 8 waves each own 64M x 64N, A prefetched one
// K-step ahead. 2 blocks/CU so phase-0 HBM reads overlap compute/writes.

#define S_SCALE 32.0f
#define MARGIN  0.35f
#define T_BOOST 0.2f
#define EPSN    1e-12f

constexpr int Bn = 512;      // batch
constexpr int Dn = 512;      // dim
constexpr int Cn = 100000;   // classes
constexpr int BN = 64;       // classes per block

typedef __attribute__((ext_vector_type(8))) short bf16x8;
typedef __attribute__((ext_vector_type(4))) float f32x4;

static __device__ inline unsigned short f32_bf16(float f) {
    unsigned int u = __float_as_uint(f);
    u += 0x7FFFu + ((u >> 16) & 1u);     // round-to-nearest-even
    return (unsigned short)(u >> 16);
}

// packed A layout: byte = (g<<14) + (s<<10) + (lane<<4) + j*2
//   g = row>>4, s = col>>5, lane = ((col>>3)&3)*16 + (row&15), j = col&7
// so frag (g, s) is one contiguous 1KB block, 16B per lane.
__global__ __launch_bounds__(256) void prep_kernel(const float* __restrict__ in,
                                                   const float* __restrict__ w,
                                                   const int* __restrict__ label,
                                                   float* __restrict__ gt,
                                                   unsigned short* __restrict__ in_p) {
    int b = blockIdx.x, t = threadIdx.x;
    const float* irow = in + (size_t)b * Dn;
    int lab = label[b];
    const float* wrow = w + (size_t)lab * Dn;
    int c = 2 * t;
    float xa = irow[c], xb = irow[c + 1];
    float ya = wrow[c], yb = wrow[c + 1];
    float s_ii = xa*xa + xb*xb, s_ww = ya*ya + yb*yb, s_iw = xa*ya + xb*yb;
    #pragma unroll
    for (int off = 32; off; off >>= 1) {
        s_ii += __shfl_xor(s_ii, off);
        s_ww += __shfl_xor(s_ww, off);
        s_iw += __shfl_xor(s_iw, off);
    }
    __shared__ float r0[4], r1[4], r2[4], bc[1];
    int wid = t >> 6;
    if ((t & 63) == 0) { r0[wid] = s_ii; r1[wid] = s_ww; r2[wid] = s_iw; }
    __syncthreads();
    if (t == 0) {
        float a  = r0[0] + r0[1] + r0[2] + r0[3];
        float cc = r1[0] + r1[1] + r1[2] + r1[3];
        float d  = r2[0] + r2[1] + r2[2] + r2[3];
        float inv_i = 1.0f / fmaxf(sqrtf(a), EPSN);
        float g = d * inv_i / fmaxf(sqrtf(cc), EPSN);
        gt[b] = fminf(fmaxf(g, -1.0f), 1.0f);
        bc[0] = inv_i;
    }
    __syncthreads();
    float inv_i = bc[0];
    int g = b >> 4, l15 = b & 15;
    int s = t >> 4, lk = (t >> 2) & 3, j2 = (t & 3) * 4;   // j*2 bytes
    int lane = lk * 16 + l15;
    unsigned int off = (unsigned)((g << 14) + (s << 10) + (lane << 4)) + j2;
    unsigned int h0 = f32_bf16(xa * inv_i), h1 = f32_bf16(xb * inv_i);
    *(unsigned int*)((char*)in_p + off) = h0 | (h1 << 16);
}

// ---------------- fused norm+convert+GEMM+margin ----------------
__global__ __launch_bounds__(512, 4) void gemm_kernel(const unsigned short* __restrict__ in_p,
                                                      const float* __restrict__ w,
                                                      const float* __restrict__ gt,
                                                      const int* __restrict__ label,
                                                      float* __restrict__ out) {
    __shared__ unsigned short Bs[BN * 512];   // 64 KB
    char* bsb = (char*)Bs;
    int t = threadIdx.x, wid = t >> 6, lane = t & 63;
    int cbase = blockIdx.x * BN;

    // ---- phase 0: W rows -> invnorm -> bf16 -> swizzled LDS ----
    {
        int rl = (wid << 3) | (lane >> 3);        // local row 0..63, 8 lanes/row
        int rg = cbase + rl; if (rg >= Cn) rg = Cn - 1;
        const float* wr = w + (size_t)rg * Dn;
        int kc = lane & 7;
        // pass 1: sumsq (streaming, low reg pressure)
        float ssum = 0.f;
        #pragma unroll 4
        for (int q = 0; q < 16; ++q) {
            f32x4 v = *(const f32x4*)(wr + kc * 8 + (q >> 1) * 64 + (q & 1) * 4);
            ssum += v[0]*v[0] + v[1]*v[1] + v[2]*v[2] + v[3]*v[3];
        }
        ssum += __shfl_xor(ssum, 1); ssum += __shfl_xor(ssum, 2); ssum += __shfl_xor(ssum, 4);
        float invn = 1.0f / fmaxf(sqrtf(ssum), EPSN);
        // pass 2: reload (L2/L3-hot), convert, swizzled LDS write
        #pragma unroll 2
        for (int i = 0; i < 8; ++i) {
            f32x4 v0 = *(const f32x4*)(wr + kc * 8 + i * 64);
            f32x4 v1 = *(const f32x4*)(wr + kc * 8 + i * 64 + 4);
            bf16x8 hv;
            #pragma unroll
            for (int j = 0; j < 4; ++j) {
                hv[j]     = (short)f32_bf16(v0[j] * invn);
                hv[4 + j] = (short)f32_bf16(v1[j] * invn);
            }
            unsigned int off = (unsigned)(((rl << 10) + (kc << 4) + (i << 7)) ^ ((rl & 7) << 4));
            *(bf16x8*)(bsb + off) = hv;
        }
    }
    __syncthreads();                              // the ONLY barrier

    // ---- K loop: A from packed L2 buffer (coalesced), B from LDS ----
    int l15 = lane & 15, lk = lane >> 4;
    const char* ap = (const char*)in_p + ((wid * 4) << 14) + (lane << 4);

    f32x4 acc[4][4];
    #pragma unroll
    for (int m = 0; m < 4; ++m)
        #pragma unroll
        for (int n = 0; n < 4; ++n) acc[m][n] = (f32x4){0.f, 0.f, 0.f, 0.f};

    bf16x8 a0[4], a1[4], bfrag[4];
    #pragma unroll
    for (int mf = 0; mf < 4; ++mf) a0[mf] = *(const bf16x8*)(ap + (mf << 14));

    for (int s2 = 0; s2 < 8; ++s2) {
        int se = s2 * 2, so = se + 1;
        // prefetch odd step's A
        #pragma unroll
        for (int mf = 0; mf < 4; ++mf)
            a1[mf] = *(const bf16x8*)(ap + (mf << 14) + (so << 10));
        // even step
        #pragma unroll
        for (int nf = 0; nf < 4; ++nf) {
            int br = nf * 16 + l15;
            bfrag[nf] = *(const bf16x8*)(bsb + ((((br << 10) + (se << 6) + (lk << 4))) ^ ((br & 7) << 4)));
        }
        #pragma unroll
        for (int mf = 0; mf < 4; ++mf)
            #pragma unroll
            for (int nf = 0; nf < 4; ++nf)
                acc[mf][nf] = __builtin_amdgcn_mfma_f32_16x16x32_bf16(a0[mf], bfrag[nf], acc[mf][nf], 0, 0, 0);
        // prefetch next even step's A
        if (s2 < 7) {
            #pragma unroll
            for (int mf = 0; mf < 4; ++mf)
                a0[mf] = *(const bf16x8*)(ap + (mf << 14) + ((se + 2) << 10));
        }
        // odd step
        #pragma unroll
        for (int nf = 0; nf < 4; ++nf) {
            int br = nf * 16 + l15;
            bfrag[nf] = *(const bf16x8*)(bsb + ((((br << 10) + (so << 6) + (lk << 4))) ^ ((br & 7) << 4)));
        }
        #pragma unroll
        for (int mf = 0; mf < 4; ++mf)
            #pragma unroll
            for (int nf = 0; nf < 4; ++nf)
                acc[mf][nf] = __builtin_amdgcn_mfma_f32_16x16x32_bf16(a1[mf], bfrag[nf], acc[mf][nf], 0, 0, 0);
    }

    // ---- epilogue: clamp, margin, label scatter, scale; nt stores ----
    #pragma unroll
    for (int mf = 0; mf < 4; ++mf) {
        #pragma unroll
        for (int r = 0; r < 4; ++r) {
            int b_row = wid * 64 + mf * 16 + lk * 4 + r;
            float thr = gt[b_row] - MARGIN;
            int lab   = label[b_row];
            float gv  = thr * S_SCALE;
            size_t obase = (size_t)b_row * Cn;
            #pragma unroll
            for (int nf = 0; nf < 4; ++nf) {
                int c = cbase + nf * 16 + l15;
                if (c < Cn) {
                    float cosv = acc[mf][nf][r];
                    cosv = fminf(fmaxf(cosv, -1.0f), 1.0f);
                    float o = (cosv > thr) ? ((T_BOOST + 1.0f) * cosv + T_BOOST) : cosv;
                    o *= S_SCALE;
                    if (c == lab) o = gv;
                    __builtin_nontemporal_store(o, &out[obase + c]);
                }
            }
        }
    }
}

extern "C" void kernel_launch(void* const* d_in, const int* in_sizes, int n_in,
                              void* d_out, int out_size, void* d_ws, size_t ws_size,
                              hipStream_t stream) {
    const float* in  = (const float*)d_in[0];
    const float* w   = (const float*)d_in[1];
    const int* label = (const int*)d_in[2];
    float* out = (float*)d_out;

    char* ws = (char*)d_ws;
    float* gt            = (float*)ws;                   // 512 f32
    unsigned short* in_p = (unsigned short*)(ws + 4096); // packed 512KB

    prep_kernel<<<dim3(Bn), dim3(256), 0, stream>>>(in, w, label, gt, in_p);
    gemm_kernel<<<dim3((Cn + BN - 1) / BN), dim3(512), 0, stream>>>(in_p, w, gt, label, out);
}